// Round 8
// baseline (648.330 us; speedup 1.0000x reference)
//
#include <hip/hip_runtime.h>
#include <hip/hip_bf16.h>

// Problem constants (fixed by the reference)
#define NN 50000
#define FIN 128
#define NH 2
#define C1 64
#define C2 32
#define NE 800000
#define NEG 0.2f

typedef unsigned int uint32;

__device__ __forceinline__ float lrelu(float v) { return v > 0.0f ? v : NEG * v; }
__device__ __forceinline__ float dot4(float4 a, float4 b) {
    return a.x * b.x + a.y * b.y + a.z * b.z + a.w * b.w;
}
// pack two f32 -> bf16x2 (round-to-nearest-even; inputs finite)
__device__ __forceinline__ uint32 packbf2(float a, float b) {
    uint32 ua = __float_as_uint(a), ub = __float_as_uint(b);
    ua += 0x7fffu + ((ua >> 16) & 1u);
    ub += 0x7fffu + ((ub >> 16) & 1u);
    return (ua >> 16) | (ub & 0xffff0000u);
}

// ---------------- CSR build ----------------
__global__ void zero_ints(int* __restrict__ a, int n) {
    for (int i = blockIdx.x * blockDim.x + threadIdx.x; i < n;
         i += gridDim.x * blockDim.x) a[i] = 0;
}

__global__ void hist_dst(const int* __restrict__ ei, int* __restrict__ deg) {
    const int i = blockIdx.x * blockDim.x + threadIdx.x;
    if (i >= NE) return;
    atomicAdd(&deg[ei[NE + i]], 1);
}

__global__ void scan_blocks(const int* __restrict__ deg, int* __restrict__ offs,
                            int* __restrict__ bsum) {
    __shared__ int sm[256];
    const int t = threadIdx.x;
    const int i = blockIdx.x * 256 + t;
    const int v = (i < NN) ? deg[i] : 0;
    sm[t] = v;
    __syncthreads();
    int x = v;
    #pragma unroll
    for (int d = 1; d < 256; d <<= 1) {
        const int y = (t >= d) ? sm[t - d] : 0;
        __syncthreads();
        x += y; sm[t] = x;
        __syncthreads();
    }
    if (i < NN) offs[i] = x - v;
    if (t == 255) bsum[blockIdx.x] = x;
}

__global__ void scan_bsums(int* __restrict__ bsum, int nb) {
    __shared__ int sm[256];
    const int t = threadIdx.x;
    const int v = (t < nb) ? bsum[t] : 0;
    sm[t] = v;
    __syncthreads();
    int x = v;
    #pragma unroll
    for (int d = 1; d < 256; d <<= 1) {
        const int y = (t >= d) ? sm[t - d] : 0;
        __syncthreads();
        x += y; sm[t] = x;
        __syncthreads();
    }
    if (t < nb) bsum[t] = x - v;
}

__global__ void scan_add(int* __restrict__ offs, const int* __restrict__ bsum) {
    const int i = blockIdx.x * 256 + threadIdx.x;
    if (i < NN) offs[i] += bsum[blockIdx.x];
}

__global__ void csr_scatter(const int* __restrict__ ei, const int* __restrict__ offs,
                            int* __restrict__ fill, int* __restrict__ esrc) {
    const int i = blockIdx.x * blockDim.x + threadIdx.x;
    if (i >= NE) return;
    const int src = ei[i], dst = ei[NE + i];
    const int pos = offs[dst] + atomicAdd(&fill[dst], 1);
    esrc[pos] = src;
}

// ------- GEMM (K=128) double-buffered, reg-blocked, fused epilogue ----------
// Lane g owns 4 float4 col chunks at stride CS=BN/4 (conflict-free ds_read_b128).
// RPT rows per lane (rows r + NR*p). Epilogue options: Y f32, H16 bf16, att dots.
template<int BN, int RPT, bool RELU_BIAS, bool WRITE_Y, bool WRITE_H16>
__global__ __launch_bounds__(256) void gemm_k128(const float* __restrict__ X,
                                                 const float* __restrict__ Wm,
                                                 const float* __restrict__ bias,
                                                 const float* __restrict__ attS,
                                                 const float* __restrict__ attD,
                                                 float* __restrict__ Y,
                                                 uint32* __restrict__ H16,
                                                 float* __restrict__ asrcO,
                                                 float* __restrict__ adstO, int M) {
    constexpr int GROUPS = BN / 16;        // 8 (BN=128) or 4 (BN=64)
    constexpr int NR = 256 / GROUPS;       // r positions: 32 or 64
    constexpr int BM = NR * RPT;           // 64 rows/block
    constexpr int CS = BN / 4;
    constexpr int NXT = BM * 8 / 256;      // per-thread X float4s per kk (2)
    constexpr int NWT = 32 * BN / 4 / 256; // per-thread W float4s per kk (4 or 2)
    __shared__ __align__(16) float Xs[2][BM][33];
    __shared__ __align__(16) float Ws[2][32][BN];

    const int tid = threadIdx.x;
    const int r  = tid / GROUPS;
    const int g  = tid % GROUPS;
    const int rowBase = blockIdx.x * BM;

    float4 xreg[NXT], wreg[NWT];

    auto stage_load = [&](int kk) {
        #pragma unroll
        for (int t = 0; t < NXT; ++t) {
            const int i = tid + 256 * t;
            const int xr = i >> 3, xc = (i & 7) * 4;
            const int grow = rowBase + xr;
            float4 v = {0, 0, 0, 0};
            if (grow < M) {
                v = *reinterpret_cast<const float4*>(&X[grow * FIN + kk * 32 + xc]);
                if (RELU_BIAS) {
                    const float4 b = *reinterpret_cast<const float4*>(&bias[kk * 32 + xc]);
                    v.x = fmaxf(v.x + b.x, 0.0f);
                    v.y = fmaxf(v.y + b.y, 0.0f);
                    v.z = fmaxf(v.z + b.z, 0.0f);
                    v.w = fmaxf(v.w + b.w, 0.0f);
                }
            }
            xreg[t] = v;
        }
        #pragma unroll
        for (int t = 0; t < NWT; ++t) {
            const int i = tid + 256 * t;
            const int wr = i / (BN / 4), wc = (i % (BN / 4)) * 4;
            wreg[t] = *reinterpret_cast<const float4*>(&Wm[(kk * 32 + wr) * BN + wc]);
        }
    };
    auto stage_write = [&](int b) {
        #pragma unroll
        for (int t = 0; t < NXT; ++t) {
            const int i = tid + 256 * t;
            const int xr = i >> 3, xc = (i & 7) * 4;
            Xs[b][xr][xc]     = xreg[t].x;
            Xs[b][xr][xc + 1] = xreg[t].y;
            Xs[b][xr][xc + 2] = xreg[t].z;
            Xs[b][xr][xc + 3] = xreg[t].w;
        }
        #pragma unroll
        for (int t = 0; t < NWT; ++t) {
            const int i = tid + 256 * t;
            const int wr = i / (BN / 4), wc = (i % (BN / 4)) * 4;
            *reinterpret_cast<float4*>(&Ws[b][wr][wc]) = wreg[t];
        }
    };

    float4 acc[RPT][4];
    #pragma unroll
    for (int p = 0; p < RPT; ++p)
        #pragma unroll
        for (int j = 0; j < 4; ++j) acc[p][j] = {0, 0, 0, 0};

    stage_load(0);
    stage_write(0);
    __syncthreads();
    int cur = 0;
    for (int kk = 0; kk < 4; ++kk) {
        if (kk < 3) stage_load(kk + 1);
        #pragma unroll
        for (int k = 0; k < 32; ++k) {
            float xv[RPT];
            #pragma unroll
            for (int p = 0; p < RPT; ++p) xv[p] = Xs[cur][r + NR * p][k];
            const float4 w0 = *reinterpret_cast<const float4*>(&Ws[cur][k][g * 4]);
            const float4 w1 = *reinterpret_cast<const float4*>(&Ws[cur][k][g * 4 + CS]);
            const float4 w2 = *reinterpret_cast<const float4*>(&Ws[cur][k][g * 4 + 2 * CS]);
            const float4 w3 = *reinterpret_cast<const float4*>(&Ws[cur][k][g * 4 + 3 * CS]);
            #pragma unroll
            for (int p = 0; p < RPT; ++p) {
                acc[p][0].x += xv[p] * w0.x; acc[p][0].y += xv[p] * w0.y;
                acc[p][0].z += xv[p] * w0.z; acc[p][0].w += xv[p] * w0.w;
                acc[p][1].x += xv[p] * w1.x; acc[p][1].y += xv[p] * w1.y;
                acc[p][1].z += xv[p] * w1.z; acc[p][1].w += xv[p] * w1.w;
                acc[p][2].x += xv[p] * w2.x; acc[p][2].y += xv[p] * w2.y;
                acc[p][2].z += xv[p] * w2.z; acc[p][2].w += xv[p] * w2.w;
                acc[p][3].x += xv[p] * w3.x; acc[p][3].y += xv[p] * w3.y;
                acc[p][3].z += xv[p] * w3.z; acc[p][3].w += xv[p] * w3.w;
            }
        }
        if (kk < 3) {
            stage_write(cur ^ 1);
            __syncthreads();
            cur ^= 1;
        }
    }

    const float4* avs = reinterpret_cast<const float4*>(attS);
    const float4* avd = reinterpret_cast<const float4*>(attD);
    #pragma unroll
    for (int p = 0; p < RPT; ++p) {
        const int grow = rowBase + r + NR * p;
        if (grow < M) {
            if (WRITE_Y) {
                float* yrow = &Y[grow * BN + g * 4];
                *reinterpret_cast<float4*>(yrow)          = acc[p][0];
                *reinterpret_cast<float4*>(yrow + CS)     = acc[p][1];
                *reinterpret_cast<float4*>(yrow + 2 * CS) = acc[p][2];
                *reinterpret_cast<float4*>(yrow + 3 * CS) = acc[p][3];
            }
            if (WRITE_H16) {
                uint32* hrow = &H16[grow * (BN / 2)];
                #pragma unroll
                for (int j = 0; j < 4; ++j) {
                    uint2 u;
                    u.x = packbf2(acc[p][j].x, acc[p][j].y);
                    u.y = packbf2(acc[p][j].z, acc[p][j].w);
                    *reinterpret_cast<uint2*>(&hrow[g * 2 + j * (CS / 2)]) = u;
                }
            }
        }
        float ps0 = dot4(acc[p][0], avs[g])              + dot4(acc[p][1], avs[g + GROUPS]);
        float ps1 = dot4(acc[p][2], avs[g + 2 * GROUPS]) + dot4(acc[p][3], avs[g + 3 * GROUPS]);
        float pd0 = dot4(acc[p][0], avd[g])              + dot4(acc[p][1], avd[g + GROUPS]);
        float pd1 = dot4(acc[p][2], avd[g + 2 * GROUPS]) + dot4(acc[p][3], avd[g + 3 * GROUPS]);
        #pragma unroll
        for (int d = 1; d < GROUPS; d <<= 1) {
            ps0 += __shfl_xor(ps0, d);
            ps1 += __shfl_xor(ps1, d);
            pd0 += __shfl_xor(pd0, d);
            pd1 += __shfl_xor(pd1, d);
        }
        if (g == 0 && grow < M) {
            asrcO[grow * 2]     = ps0;
            asrcO[grow * 2 + 1] = ps1;
            adstO[grow * 2]     = pd0;
            adstO[grow * 2 + 1] = pd1;
        }
    }
}

// ---------------- fused per-dst exact softmax + aggregation (layer 1) ---------
// one wave per dst; lane owns chans {2*lane, 2*lane+1}; head h = lane>>5.
// phase1: wave-parallel max (scores cached in regs); phase2: no-rescale accum.
// All H reads (incl. self-loop) from bf16 H16 [N, 64 uint32].
__global__ __launch_bounds__(256) void gat_dst1(const int* __restrict__ esrc,
                                                const int* __restrict__ offs,
                                                const uint32* __restrict__ H16,
                                                const float* __restrict__ asrc,
                                                const float* __restrict__ adst,
                                                float* __restrict__ out) {
    const int wid  = (blockIdx.x * blockDim.x + threadIdx.x) >> 6;
    const int lane = threadIdx.x & 63;
    if (wid >= NN) return;
    const int dst = wid;
    const int beg = offs[dst];
    const int end = (dst == NN - 1) ? NE : offs[dst + 1];
    const int deg = end - beg;
    const float2 ad = *reinterpret_cast<const float2*>(&adst[dst * 2]);

    int   s0  = 0;
    float pe0 = -INFINITY, pe1 = -INFINITY;
    float m0  = -INFINITY, m1  = -INFINITY;
    for (int j = lane; j < deg; j += 64) {
        const int s = esrc[beg + j];
        const float2 a = *reinterpret_cast<const float2*>(&asrc[s * 2]);
        const float f0 = lrelu(a.x + ad.x);
        const float f1 = lrelu(a.y + ad.y);
        if (j == lane) { s0 = s; pe0 = f0; pe1 = f1; }
        m0 = fmaxf(m0, f0); m1 = fmaxf(m1, f1);
    }
    const float2 aself = *reinterpret_cast<const float2*>(&asrc[dst * 2]);
    const float es0 = lrelu(aself.x + ad.x);
    const float es1 = lrelu(aself.y + ad.y);
    m0 = fmaxf(m0, es0); m1 = fmaxf(m1, es1);
    #pragma unroll
    for (int d = 1; d < 64; d <<= 1) {
        m0 = fmaxf(m0, __shfl_xor(m0, d));
        m1 = fmaxf(m1, __shfl_xor(m1, d));
    }
    const int h = lane >> 5;
    const float m = h ? m1 : m0;

    // self-loop (bf16 H)
    float l;
    float2 acc;
    {
        const float px = __expf((h ? es1 : es0) - m);
        l = px;
        const uint32 u = H16[dst * 64 + lane];
        acc.x = px * __uint_as_float(u << 16);
        acc.y = px * __uint_as_float(u & 0xffff0000u);
    }
    const int jmax = deg < 64 ? deg : 64;
    for (int j = 0; j < jmax; ++j) {
        const int s = __shfl(s0, j);
        const float t0 = __shfl(pe0, j), t1 = __shfl(pe1, j);
        const float p = __expf((h ? t1 : t0) - m);
        const uint32 u = H16[s * 64 + lane];
        l += p;
        acc.x += p * __uint_as_float(u << 16);
        acc.y += p * __uint_as_float(u & 0xffff0000u);
    }
    for (int j = 64; j < deg; ++j) {          // astronomically rare (deg>64)
        const int s = esrc[beg + j];
        const float2 a = *reinterpret_cast<const float2*>(&asrc[s * 2]);
        const float p = __expf(lrelu((h ? a.y : a.x) + (h ? ad.y : ad.x)) - m);
        const uint32 u = H16[s * 64 + lane];
        l += p;
        acc.x += p * __uint_as_float(u << 16);
        acc.y += p * __uint_as_float(u & 0xffff0000u);
    }
    const float inv = 1.0f / (l + 1e-16f);
    float2 res; res.x = acc.x * inv; res.y = acc.y * inv;
    *reinterpret_cast<float2*>(&out[dst * 128 + lane * 2]) = res;
}

// ---------------- layer 2: same structure + head-mean; f32 H [N,64] -----------
__global__ __launch_bounds__(256) void gat_dst2(const int* __restrict__ esrc,
                                                const int* __restrict__ offs,
                                                const float* __restrict__ Hf,
                                                const float* __restrict__ asrc,
                                                const float* __restrict__ adst,
                                                const float* __restrict__ bias,
                                                float* __restrict__ out) {
    const int wid  = (blockIdx.x * blockDim.x + threadIdx.x) >> 6;
    const int lane = threadIdx.x & 63;
    if (wid >= NN) return;
    const int dst = wid;
    const int beg = offs[dst];
    const int end = (dst == NN - 1) ? NE : offs[dst + 1];
    const int deg = end - beg;
    const float2 ad = *reinterpret_cast<const float2*>(&adst[dst * 2]);

    int   s0  = 0;
    float pe0 = -INFINITY, pe1 = -INFINITY;
    float m0  = -INFINITY, m1  = -INFINITY;
    for (int j = lane; j < deg; j += 64) {
        const int s = esrc[beg + j];
        const float2 a = *reinterpret_cast<const float2*>(&asrc[s * 2]);
        const float f0 = lrelu(a.x + ad.x);
        const float f1 = lrelu(a.y + ad.y);
        if (j == lane) { s0 = s; pe0 = f0; pe1 = f1; }
        m0 = fmaxf(m0, f0); m1 = fmaxf(m1, f1);
    }
    const float2 aself = *reinterpret_cast<const float2*>(&asrc[dst * 2]);
    const float es0 = lrelu(aself.x + ad.x);
    const float es1 = lrelu(aself.y + ad.y);
    m0 = fmaxf(m0, es0); m1 = fmaxf(m1, es1);
    #pragma unroll
    for (int d = 1; d < 64; d <<= 1) {
        m0 = fmaxf(m0, __shfl_xor(m0, d));
        m1 = fmaxf(m1, __shfl_xor(m1, d));
    }
    const int h = lane >> 5;
    const float m = h ? m1 : m0;

    float l, acc;
    {
        const float px = __expf((h ? es1 : es0) - m);
        l = px;
        acc = px * Hf[dst * 64 + lane];
    }
    const int jmax = deg < 64 ? deg : 64;
    for (int j = 0; j < jmax; ++j) {
        const int s = __shfl(s0, j);
        const float t0 = __shfl(pe0, j), t1 = __shfl(pe1, j);
        const float p = __expf((h ? t1 : t0) - m);
        const float hv = Hf[s * 64 + lane];
        l += p;
        acc += p * hv;
    }
    for (int j = 64; j < deg; ++j) {          // astronomically rare
        const int s = esrc[beg + j];
        const float2 a = *reinterpret_cast<const float2*>(&asrc[s * 2]);
        const float p = __expf(lrelu((h ? a.y : a.x) + (h ? ad.y : ad.x)) - m);
        l += p;
        acc += p * Hf[s * 64 + lane];
    }
    float r = acc / (l + 1e-16f);
    r += __shfl_xor(r, 32);                   // combine heads
    if (lane < 32) out[dst * 32 + lane] = 0.5f * r + bias[lane];
}

// ---------------- launch ----------------
extern "C" void kernel_launch(void* const* d_in, const int* in_sizes, int n_in,
                              void* d_out, int out_size, void* d_ws, size_t ws_size,
                              hipStream_t stream) {
    const float* x   = (const float*)d_in[0];
    const int*   ei  = (const int*)d_in[1];
    const float* W1  = (const float*)d_in[2];
    const float* as1 = (const float*)d_in[3];
    const float* ad1 = (const float*)d_in[4];
    const float* b1  = (const float*)d_in[5];
    const float* W2  = (const float*)d_in[6];
    const float* as2 = (const float*)d_in[7];
    const float* ad2 = (const float*)d_in[8];
    const float* b2  = (const float*)d_in[9];
    float* out = (float*)d_out;

    // Workspace: 14.15 M floats = 56.6 MB — identical demand to the round-4
    // layout that ran successfully (do not exceed without evidence of ws_size).
    float* ws = (float*)d_ws;
    size_t off = 0;
    float* out1  = ws + off; off += (size_t)NN * FIN;   // [N,128] layer1 output (f32)
    float* h2f   = ws + off; off += (size_t)NN * C1;    // [N,64]  layer2 H (f32)
    float* asrc1 = ws + off; off += (size_t)NN * NH;
    float* adst1 = ws + off; off += (size_t)NN * NH;
    float* asrc2 = ws + off; off += (size_t)NN * NH;
    float* adst2 = ws + off; off += (size_t)NN * NH;
    uint32* h16  = (uint32*)(ws + off); off += (size_t)NN * 64;  // bf16 [N,128]
    int* ibase = (int*)(ws + off);
    int* deg   = ibase;                 // [NN]  \ adjacent: one zero_ints
    int* fill  = ibase + NN;            // [NN]  /
    int* offs  = ibase + 2 * NN;        // [NN]
    int* bsum  = ibase + 3 * NN;        // [256]
    int* esrc  = ibase + 3 * NN + 256;  // [NE]

    const int B = 256;
    constexpr int NB_SCAN = (NN + 255) / 256;   // 196

    // ---- CSR build (shared by both layers) ----
    zero_ints<<<128, B, 0, stream>>>(deg, 2 * NN);   // deg + fill
    hist_dst<<<(NE + B - 1) / B, B, 0, stream>>>(ei, deg);
    scan_blocks<<<NB_SCAN, 256, 0, stream>>>(deg, offs, bsum);
    scan_bsums<<<1, 256, 0, stream>>>(bsum, NB_SCAN);
    scan_add<<<NB_SCAN, 256, 0, stream>>>(offs, bsum);
    csr_scatter<<<(NE + B - 1) / B, B, 0, stream>>>(ei, offs, fill, esrc);

    // ---- layer 1 ----  (gemm writes bf16 H only; no f32 Y)
    gemm_k128<128, 2, false, false, true><<<(NN + 63) / 64, B, 0, stream>>>(
        x, W1, nullptr, as1, ad1, nullptr, h16, asrc1, adst1, NN);
    gat_dst1<<<(NN * 64 + B - 1) / B, B, 0, stream>>>(
        esrc, offs, h16, asrc1, adst1, out1);

    // ---- layer 2 ----  (gemm writes f32 Y only; f32 gathers)
    gemm_k128<64, 1, true, true, false><<<(NN + 63) / 64, B, 0, stream>>>(
        out1, W2, b1, as2, ad2, h2f, nullptr, asrc2, adst2, NN);
    gat_dst2<<<(NN * 64 + B - 1) / B, B, 0, stream>>>(
        esrc, offs, h2f, asrc2, adst2, b2, out);
}

// Round 9
// 383.368 us; speedup vs baseline: 1.6911x; 1.6911x over previous
//
#include <hip/hip_runtime.h>
#include <hip/hip_bf16.h>

// Problem constants (fixed by the reference)
#define NN 50000
#define FIN 128
#define NH 2
#define C1 64
#define C2 32
#define NE 800000
#define NEG 0.2f

typedef unsigned int uint32;

__device__ __forceinline__ float lrelu(float v) { return v > 0.0f ? v : NEG * v; }
__device__ __forceinline__ float dot4(float4 a, float4 b) {
    return a.x * b.x + a.y * b.y + a.z * b.z + a.w * b.w;
}
// pack two f32 -> bf16x2 (round-to-nearest-even; inputs finite)
__device__ __forceinline__ uint32 packbf2(float a, float b) {
    uint32 ua = __float_as_uint(a), ub = __float_as_uint(b);
    ua += 0x7fffu + ((ua >> 16) & 1u);
    ub += 0x7fffu + ((ub >> 16) & 1u);
    return (ua >> 16) | (ub & 0xffff0000u);
}

// ---------------- CSR build ----------------
__global__ void zero_ints(int* __restrict__ a, int n) {
    for (int i = blockIdx.x * blockDim.x + threadIdx.x; i < n;
         i += gridDim.x * blockDim.x) a[i] = 0;
}

__global__ void hist_dst(const int* __restrict__ ei, int* __restrict__ deg) {
    const int i = blockIdx.x * blockDim.x + threadIdx.x;
    if (i >= NE) return;
    atomicAdd(&deg[ei[NE + i]], 1);
}

__global__ void scan_blocks(const int* __restrict__ deg, int* __restrict__ offs,
                            int* __restrict__ bsum) {
    __shared__ int sm[256];
    const int t = threadIdx.x;
    const int i = blockIdx.x * 256 + t;
    const int v = (i < NN) ? deg[i] : 0;
    sm[t] = v;
    __syncthreads();
    int x = v;
    #pragma unroll
    for (int d = 1; d < 256; d <<= 1) {
        const int y = (t >= d) ? sm[t - d] : 0;
        __syncthreads();
        x += y; sm[t] = x;
        __syncthreads();
    }
    if (i < NN) offs[i] = x - v;
    if (t == 255) bsum[blockIdx.x] = x;
}

__global__ void scan_bsums(int* __restrict__ bsum, int nb) {
    __shared__ int sm[256];
    const int t = threadIdx.x;
    const int v = (t < nb) ? bsum[t] : 0;
    sm[t] = v;
    __syncthreads();
    int x = v;
    #pragma unroll
    for (int d = 1; d < 256; d <<= 1) {
        const int y = (t >= d) ? sm[t - d] : 0;
        __syncthreads();
        x += y; sm[t] = x;
        __syncthreads();
    }
    if (t < nb) bsum[t] = x - v;
}

__global__ void scan_add(int* __restrict__ offs, const int* __restrict__ bsum) {
    const int i = blockIdx.x * 256 + threadIdx.x;
    if (i < NN) offs[i] += bsum[blockIdx.x];
}

__global__ void csr_scatter(const int* __restrict__ ei, const int* __restrict__ offs,
                            int* __restrict__ fill, int* __restrict__ esrc) {
    const int i = blockIdx.x * blockDim.x + threadIdx.x;
    if (i >= NE) return;
    const int src = ei[i], dst = ei[NE + i];
    const int pos = offs[dst] + atomicAdd(&fill[dst], 1);
    esrc[pos] = src;
}

// ------- GEMM (K=128), round-4 proven structure + epilogue options ----------
// Single LDS buffer, direct load->LDS staging (NO reg staging across the FMA
// loop -- round-5's xreg/wreg + dbuf spilled to scratch: VGPR 256, 600MB spill).
// Lane g owns 4 float4 col chunks at stride CS=BN/4 (conflict-free ds_read_b128).
// __launch_bounds__(256,2): cap VGPR at 128 so pressure can't silently explode.
template<int BN, bool RELU_BIAS, bool WRITE_Y, bool WRITE_H16>
__global__ __launch_bounds__(256, 2) void gemm_k128(const float* __restrict__ X,
                                                    const float* __restrict__ Wm,
                                                    const float* __restrict__ bias,
                                                    const float* __restrict__ attS,
                                                    const float* __restrict__ attD,
                                                    float* __restrict__ Y,
                                                    uint32* __restrict__ H16,
                                                    float* __restrict__ asrcO,
                                                    float* __restrict__ adstO, int M) {
    constexpr int GROUPS = BN / 16;      // 8 (BN=128) or 4 (BN=64)
    constexpr int BM = 256 / GROUPS;     // 32 or 64
    constexpr int CS = BN / 4;           // column stride between a lane's chunks
    __shared__ __align__(16) float Xs[BM][33];
    __shared__ __align__(16) float Ws[32][BN];

    const int tid = threadIdx.x;
    const int r  = tid / GROUPS;
    const int g  = tid % GROUPS;
    const int rowBase = blockIdx.x * BM;

    float4 acc0 = {0,0,0,0}, acc1 = {0,0,0,0}, acc2 = {0,0,0,0}, acc3 = {0,0,0,0};

    for (int kk = 0; kk < 4; ++kk) {
        constexpr int XV = BM * 8;
        #pragma unroll
        for (int i = tid; i < XV; i += 256) {
            const int xr = i >> 3, xc = (i & 7) * 4;
            const int grow = rowBase + xr;
            float4 v = {0,0,0,0};
            if (grow < M) {
                v = *reinterpret_cast<const float4*>(&X[grow * FIN + kk * 32 + xc]);
                if (RELU_BIAS) {
                    const float4 b = *reinterpret_cast<const float4*>(&bias[kk * 32 + xc]);
                    v.x = fmaxf(v.x + b.x, 0.0f);
                    v.y = fmaxf(v.y + b.y, 0.0f);
                    v.z = fmaxf(v.z + b.z, 0.0f);
                    v.w = fmaxf(v.w + b.w, 0.0f);
                }
            }
            Xs[xr][xc] = v.x; Xs[xr][xc+1] = v.y; Xs[xr][xc+2] = v.z; Xs[xr][xc+3] = v.w;
        }
        constexpr int WV = 32 * BN / 4;
        #pragma unroll
        for (int i = tid; i < WV; i += 256) {
            const int wr = i / (BN / 4), wc = (i % (BN / 4)) * 4;
            *reinterpret_cast<float4*>(&Ws[wr][wc]) =
                *reinterpret_cast<const float4*>(&Wm[(kk * 32 + wr) * BN + wc]);
        }
        __syncthreads();
        #pragma unroll
        for (int k = 0; k < 32; ++k) {
            const float xv = Xs[r][k];
            const float4 w0 = *reinterpret_cast<const float4*>(&Ws[k][g * 4]);
            const float4 w1 = *reinterpret_cast<const float4*>(&Ws[k][g * 4 + CS]);
            const float4 w2 = *reinterpret_cast<const float4*>(&Ws[k][g * 4 + 2 * CS]);
            const float4 w3 = *reinterpret_cast<const float4*>(&Ws[k][g * 4 + 3 * CS]);
            acc0.x += xv * w0.x; acc0.y += xv * w0.y; acc0.z += xv * w0.z; acc0.w += xv * w0.w;
            acc1.x += xv * w1.x; acc1.y += xv * w1.y; acc1.z += xv * w1.z; acc1.w += xv * w1.w;
            acc2.x += xv * w2.x; acc2.y += xv * w2.y; acc2.z += xv * w2.z; acc2.w += xv * w2.w;
            acc3.x += xv * w3.x; acc3.y += xv * w3.y; acc3.z += xv * w3.z; acc3.w += xv * w3.w;
        }
        __syncthreads();
    }

    const int grow = rowBase + r;
    if (grow < M) {
        if (WRITE_Y) {
            float* yrow = &Y[grow * BN + g * 4];
            *reinterpret_cast<float4*>(yrow)          = acc0;
            *reinterpret_cast<float4*>(yrow + CS)     = acc1;
            *reinterpret_cast<float4*>(yrow + 2 * CS) = acc2;
            *reinterpret_cast<float4*>(yrow + 3 * CS) = acc3;
        }
        if (WRITE_H16) {
            uint32* hrow = &H16[grow * (BN / 2)];
            uint2 u;
            u.x = packbf2(acc0.x, acc0.y); u.y = packbf2(acc0.z, acc0.w);
            *reinterpret_cast<uint2*>(&hrow[g * 2])              = u;
            u.x = packbf2(acc1.x, acc1.y); u.y = packbf2(acc1.z, acc1.w);
            *reinterpret_cast<uint2*>(&hrow[g * 2 + CS / 2])     = u;
            u.x = packbf2(acc2.x, acc2.y); u.y = packbf2(acc2.z, acc2.w);
            *reinterpret_cast<uint2*>(&hrow[g * 2 + CS])         = u;
            u.x = packbf2(acc3.x, acc3.y); u.y = packbf2(acc3.z, acc3.w);
            *reinterpret_cast<uint2*>(&hrow[g * 2 + 3 * CS / 2]) = u;
        }
    }
    // fused attention dot products; att vector float4 index = g + GROUPS*j
    const float4* avs = reinterpret_cast<const float4*>(attS);
    const float4* avd = reinterpret_cast<const float4*>(attD);
    float ps0 = dot4(acc0, avs[g])              + dot4(acc1, avs[g + GROUPS]);
    float ps1 = dot4(acc2, avs[g + 2 * GROUPS]) + dot4(acc3, avs[g + 3 * GROUPS]);
    float pd0 = dot4(acc0, avd[g])              + dot4(acc1, avd[g + GROUPS]);
    float pd1 = dot4(acc2, avd[g + 2 * GROUPS]) + dot4(acc3, avd[g + 3 * GROUPS]);
    #pragma unroll
    for (int d = 1; d < GROUPS; d <<= 1) {
        ps0 += __shfl_xor(ps0, d);
        ps1 += __shfl_xor(ps1, d);
        pd0 += __shfl_xor(pd0, d);
        pd1 += __shfl_xor(pd1, d);
    }
    if (g == 0 && grow < M) {
        asrcO[grow * 2]     = ps0;
        asrcO[grow * 2 + 1] = ps1;
        adstO[grow * 2]     = pd0;
        adstO[grow * 2 + 1] = pd1;
    }
}

// ---------------- fused per-dst exact softmax + aggregation (layer 1) ---------
// one wave per dst; lane owns chans {2*lane, 2*lane+1}; head h = lane>>5.
// phase1: wave-parallel max (scores cached in regs); phase2: no-rescale accum.
// All H reads (incl. self-loop) from bf16 H16 [N, 64 uint32].
__global__ __launch_bounds__(256) void gat_dst1(const int* __restrict__ esrc,
                                                const int* __restrict__ offs,
                                                const uint32* __restrict__ H16,
                                                const float* __restrict__ asrc,
                                                const float* __restrict__ adst,
                                                float* __restrict__ out) {
    const int wid  = (blockIdx.x * blockDim.x + threadIdx.x) >> 6;
    const int lane = threadIdx.x & 63;
    if (wid >= NN) return;
    const int dst = wid;
    const int beg = offs[dst];
    const int end = (dst == NN - 1) ? NE : offs[dst + 1];
    const int deg = end - beg;
    const float2 ad = *reinterpret_cast<const float2*>(&adst[dst * 2]);

    int   s0  = 0;
    float pe0 = -INFINITY, pe1 = -INFINITY;
    float m0  = -INFINITY, m1  = -INFINITY;
    for (int j = lane; j < deg; j += 64) {
        const int s = esrc[beg + j];
        const float2 a = *reinterpret_cast<const float2*>(&asrc[s * 2]);
        const float f0 = lrelu(a.x + ad.x);
        const float f1 = lrelu(a.y + ad.y);
        if (j == lane) { s0 = s; pe0 = f0; pe1 = f1; }
        m0 = fmaxf(m0, f0); m1 = fmaxf(m1, f1);
    }
    const float2 aself = *reinterpret_cast<const float2*>(&asrc[dst * 2]);
    const float es0 = lrelu(aself.x + ad.x);
    const float es1 = lrelu(aself.y + ad.y);
    m0 = fmaxf(m0, es0); m1 = fmaxf(m1, es1);
    #pragma unroll
    for (int d = 1; d < 64; d <<= 1) {
        m0 = fmaxf(m0, __shfl_xor(m0, d));
        m1 = fmaxf(m1, __shfl_xor(m1, d));
    }
    const int h = lane >> 5;
    const float m = h ? m1 : m0;

    // self-loop (bf16 H)
    float l;
    float2 acc;
    {
        const float px = __expf((h ? es1 : es0) - m);
        l = px;
        const uint32 u = H16[dst * 64 + lane];
        acc.x = px * __uint_as_float(u << 16);
        acc.y = px * __uint_as_float(u & 0xffff0000u);
    }
    const int jmax = deg < 64 ? deg : 64;
    for (int j = 0; j < jmax; ++j) {
        const int s = __shfl(s0, j);
        const float t0 = __shfl(pe0, j), t1 = __shfl(pe1, j);
        const float p = __expf((h ? t1 : t0) - m);
        const uint32 u = H16[s * 64 + lane];
        l += p;
        acc.x += p * __uint_as_float(u << 16);
        acc.y += p * __uint_as_float(u & 0xffff0000u);
    }
    for (int j = 64; j < deg; ++j) {          // astronomically rare (deg>64)
        const int s = esrc[beg + j];
        const float2 a = *reinterpret_cast<const float2*>(&asrc[s * 2]);
        const float p = __expf(lrelu((h ? a.y : a.x) + (h ? ad.y : ad.x)) - m);
        const uint32 u = H16[s * 64 + lane];
        l += p;
        acc.x += p * __uint_as_float(u << 16);
        acc.y += p * __uint_as_float(u & 0xffff0000u);
    }
    const float inv = 1.0f / (l + 1e-16f);
    float2 res; res.x = acc.x * inv; res.y = acc.y * inv;
    *reinterpret_cast<float2*>(&out[dst * 128 + lane * 2]) = res;
}

// ---------------- layer 2: same structure + head-mean; f32 H [N,64] -----------
__global__ __launch_bounds__(256) void gat_dst2(const int* __restrict__ esrc,
                                                const int* __restrict__ offs,
                                                const float* __restrict__ Hf,
                                                const float* __restrict__ asrc,
                                                const float* __restrict__ adst,
                                                const float* __restrict__ bias,
                                                float* __restrict__ out) {
    const int wid  = (blockIdx.x * blockDim.x + threadIdx.x) >> 6;
    const int lane = threadIdx.x & 63;
    if (wid >= NN) return;
    const int dst = wid;
    const int beg = offs[dst];
    const int end = (dst == NN - 1) ? NE : offs[dst + 1];
    const int deg = end - beg;
    const float2 ad = *reinterpret_cast<const float2*>(&adst[dst * 2]);

    int   s0  = 0;
    float pe0 = -INFINITY, pe1 = -INFINITY;
    float m0  = -INFINITY, m1  = -INFINITY;
    for (int j = lane; j < deg; j += 64) {
        const int s = esrc[beg + j];
        const float2 a = *reinterpret_cast<const float2*>(&asrc[s * 2]);
        const float f0 = lrelu(a.x + ad.x);
        const float f1 = lrelu(a.y + ad.y);
        if (j == lane) { s0 = s; pe0 = f0; pe1 = f1; }
        m0 = fmaxf(m0, f0); m1 = fmaxf(m1, f1);
    }
    const float2 aself = *reinterpret_cast<const float2*>(&asrc[dst * 2]);
    const float es0 = lrelu(aself.x + ad.x);
    const float es1 = lrelu(aself.y + ad.y);
    m0 = fmaxf(m0, es0); m1 = fmaxf(m1, es1);
    #pragma unroll
    for (int d = 1; d < 64; d <<= 1) {
        m0 = fmaxf(m0, __shfl_xor(m0, d));
        m1 = fmaxf(m1, __shfl_xor(m1, d));
    }
    const int h = lane >> 5;
    const float m = h ? m1 : m0;

    float l, acc;
    {
        const float px = __expf((h ? es1 : es0) - m);
        l = px;
        acc = px * Hf[dst * 64 + lane];
    }
    const int jmax = deg < 64 ? deg : 64;
    for (int j = 0; j < jmax; ++j) {
        const int s = __shfl(s0, j);
        const float t0 = __shfl(pe0, j), t1 = __shfl(pe1, j);
        const float p = __expf((h ? t1 : t0) - m);
        const float hv = Hf[s * 64 + lane];
        l += p;
        acc += p * hv;
    }
    for (int j = 64; j < deg; ++j) {          // astronomically rare
        const int s = esrc[beg + j];
        const float2 a = *reinterpret_cast<const float2*>(&asrc[s * 2]);
        const float p = __expf(lrelu((h ? a.y : a.x) + (h ? ad.y : ad.x)) - m);
        l += p;
        acc += p * Hf[s * 64 + lane];
    }
    float r = acc / (l + 1e-16f);
    r += __shfl_xor(r, 32);                   // combine heads
    if (lane < 32) out[dst * 32 + lane] = 0.5f * r + bias[lane];
}

// ---------------- launch ----------------
extern "C" void kernel_launch(void* const* d_in, const int* in_sizes, int n_in,
                              void* d_out, int out_size, void* d_ws, size_t ws_size,
                              hipStream_t stream) {
    const float* x   = (const float*)d_in[0];
    const int*   ei  = (const int*)d_in[1];
    const float* W1  = (const float*)d_in[2];
    const float* as1 = (const float*)d_in[3];
    const float* ad1 = (const float*)d_in[4];
    const float* b1  = (const float*)d_in[5];
    const float* W2  = (const float*)d_in[6];
    const float* as2 = (const float*)d_in[7];
    const float* ad2 = (const float*)d_in[8];
    const float* b2  = (const float*)d_in[9];
    float* out = (float*)d_out;

    // Workspace: 14.15 M floats = 56.6 MB (round-8 proven layout).
    float* ws = (float*)d_ws;
    size_t off = 0;
    float* out1  = ws + off; off += (size_t)NN * FIN;   // [N,128] layer1 output (f32)
    float* h2f   = ws + off; off += (size_t)NN * C1;    // [N,64]  layer2 H (f32)
    float* asrc1 = ws + off; off += (size_t)NN * NH;
    float* adst1 = ws + off; off += (size_t)NN * NH;
    float* asrc2 = ws + off; off += (size_t)NN * NH;
    float* adst2 = ws + off; off += (size_t)NN * NH;
    uint32* h16  = (uint32*)(ws + off); off += (size_t)NN * 64;  // bf16 [N,128]
    int* ibase = (int*)(ws + off);
    int* deg   = ibase;                 // [NN]  \ adjacent: one zero_ints
    int* fill  = ibase + NN;            // [NN]  /
    int* offs  = ibase + 2 * NN;        // [NN]
    int* bsum  = ibase + 3 * NN;        // [256]
    int* esrc  = ibase + 3 * NN + 256;  // [NE]

    const int B = 256;
    constexpr int NB_SCAN = (NN + 255) / 256;   // 196

    // ---- CSR build (shared by both layers) ----
    zero_ints<<<128, B, 0, stream>>>(deg, 2 * NN);   // deg + fill
    hist_dst<<<(NE + B - 1) / B, B, 0, stream>>>(ei, deg);
    scan_blocks<<<NB_SCAN, 256, 0, stream>>>(deg, offs, bsum);
    scan_bsums<<<1, 256, 0, stream>>>(bsum, NB_SCAN);
    scan_add<<<NB_SCAN, 256, 0, stream>>>(offs, bsum);
    csr_scatter<<<(NE + B - 1) / B, B, 0, stream>>>(ei, offs, fill, esrc);

    // ---- layer 1 ----  (gemm writes bf16 H only; no f32 Y)
    gemm_k128<128, false, false, true><<<(NN + 31) / 32, B, 0, stream>>>(
        x, W1, nullptr, as1, ad1, nullptr, h16, asrc1, adst1, NN);
    gat_dst1<<<(NN * 64 + B - 1) / B, B, 0, stream>>>(
        esrc, offs, h16, asrc1, adst1, out1);

    // ---- layer 2 ----  (gemm writes f32 Y only; f32 gathers)
    gemm_k128<64, true, true, false><<<(NN + 63) / 64, B, 0, stream>>>(
        out1, W2, b1, as2, ad2, h2f, nullptr, asrc2, adst2, NN);
    gat_dst2<<<(NN * 64 + B - 1) / B, B, 0, stream>>>(
        esrc, offs, h2f, asrc2, adst2, b2, out);
}

// Round 10
// 366.498 us; speedup vs baseline: 1.7690x; 1.0460x over previous
//
#include <hip/hip_runtime.h>
#include <hip/hip_bf16.h>

// Problem constants (fixed by the reference)
#define NN 50000
#define FIN 128
#define NH 2
#define C1 64
#define C2 32
#define NE 800000
#define NEG 0.2f

typedef unsigned int uint32;

__device__ __forceinline__ float lrelu(float v) { return v > 0.0f ? v : NEG * v; }
__device__ __forceinline__ float dot4(float4 a, float4 b) {
    return a.x * b.x + a.y * b.y + a.z * b.z + a.w * b.w;
}
// pack two f32 -> bf16x2 (round-to-nearest-even; inputs finite)
__device__ __forceinline__ uint32 packbf2(float a, float b) {
    uint32 ua = __float_as_uint(a), ub = __float_as_uint(b);
    ua += 0x7fffu + ((ua >> 16) & 1u);
    ub += 0x7fffu + ((ub >> 16) & 1u);
    return (ua >> 16) | (ub & 0xffff0000u);
}
// async 16B global -> LDS DMA. LDS dest: wave-uniform base + lane*16 (m104).
__device__ __forceinline__ void gload16(const float* g, float* l) {
    __builtin_amdgcn_global_load_lds(
        (const __attribute__((address_space(1))) unsigned int*)g,
        (__attribute__((address_space(3))) unsigned int*)l, 16, 0, 0);
}

// ---------------- CSR build ----------------
__global__ void zero_ints(int* __restrict__ a, int n) {
    for (int i = blockIdx.x * blockDim.x + threadIdx.x; i < n;
         i += gridDim.x * blockDim.x) a[i] = 0;
}

__global__ void hist_dst(const int* __restrict__ ei, int* __restrict__ deg) {
    const int i = blockIdx.x * blockDim.x + threadIdx.x;
    if (i >= NE) return;
    atomicAdd(&deg[ei[NE + i]], 1);
}

__global__ void scan_blocks(const int* __restrict__ deg, int* __restrict__ offs,
                            int* __restrict__ bsum) {
    __shared__ int sm[256];
    const int t = threadIdx.x;
    const int i = blockIdx.x * 256 + t;
    const int v = (i < NN) ? deg[i] : 0;
    sm[t] = v;
    __syncthreads();
    int x = v;
    #pragma unroll
    for (int d = 1; d < 256; d <<= 1) {
        const int y = (t >= d) ? sm[t - d] : 0;
        __syncthreads();
        x += y; sm[t] = x;
        __syncthreads();
    }
    if (i < NN) offs[i] = x - v;
    if (t == 255) bsum[blockIdx.x] = x;
}

__global__ void scan_bsums(int* __restrict__ bsum, int nb) {
    __shared__ int sm[256];
    const int t = threadIdx.x;
    const int v = (t < nb) ? bsum[t] : 0;
    sm[t] = v;
    __syncthreads();
    int x = v;
    #pragma unroll
    for (int d = 1; d < 256; d <<= 1) {
        const int y = (t >= d) ? sm[t - d] : 0;
        __syncthreads();
        x += y; sm[t] = x;
        __syncthreads();
    }
    if (t < nb) bsum[t] = x - v;
}

__global__ void scan_add(int* __restrict__ offs, const int* __restrict__ bsum) {
    const int i = blockIdx.x * 256 + threadIdx.x;
    if (i < NN) offs[i] += bsum[blockIdx.x];
}

__global__ void csr_scatter(const int* __restrict__ ei, const int* __restrict__ offs,
                            int* __restrict__ fill, int* __restrict__ esrc) {
    const int i = blockIdx.x * blockDim.x + threadIdx.x;
    if (i >= NE) return;
    const int src = ei[i], dst = ei[NE + i];
    const int pos = offs[dst] + atomicAdd(&fill[dst], 1);
    esrc[pos] = src;
}

// ------- GEMM (K=128): global_load_lds dbuf staging, RPT=2 reg blocking -------
// X stride fixed 128 (both layers). Lane g owns 4 float4 col chunks at stride
// CS=BN/4 (conflict-free ds_read_b128 on W). X stored source-swizzled:
// LDS slot d holds X[row=d>>3][f4col = (d&7) ^ (row&7)]; read with same XOR.
// No reg staging (round-5 lesson: 256 VGPR spill); DMA needs ~0 regs.
template<int BN, bool WRITE_Y, bool WRITE_H16>
__global__ __launch_bounds__(256, 2) void gemm_k128(const float* __restrict__ X,
                                                    const float* __restrict__ Wm,
                                                    const float* __restrict__ attS,
                                                    const float* __restrict__ attD,
                                                    float* __restrict__ Y,
                                                    uint32* __restrict__ H16,
                                                    float* __restrict__ asrcO,
                                                    float* __restrict__ adstO, int M) {
    constexpr int GROUPS = BN / 16;      // 8 (BN=128) or 4 (BN=64)
    constexpr int NR = 256 / GROUPS;     // 32 or 64
    constexpr int BM = NR * 2;           // 64 or 128 rows/block (RPT=2)
    constexpr int CS = BN / 4;
    constexpr int NXC = BM / 32;         // X 16B-DMAs per thread per kk (2 or 4)
    constexpr int NWC = BN / 32;         // W 16B-DMAs per thread per kk (4 or 2)
    __shared__ __align__(16) float Xs[2][BM * 32];
    __shared__ __align__(16) float Ws[2][32 * BN];

    const int tid = threadIdx.x;
    const int r  = tid / GROUPS;         // 0..NR-1 (owns rows r, r+NR)
    const int g  = tid % GROUPS;
    const int g4 = g * 4;
    const int wv = tid >> 6;             // wave id (uniform per wave)
    const int rowBase = blockIdx.x * BM;
    const int rr = r & 7;                // (r+NR)&7 == r&7 since NR%8==0

    auto stage = [&](int kk, int b) {
        float* XsB = &Xs[b][0];
        float* WsB = &Ws[b][0];
        #pragma unroll
        for (int t = 0; t < NXC; ++t) {
            const int d  = t * 256 + tid;              // slot id
            const int xr = d >> 3;
            const int kc = (d & 7) ^ (xr & 7);         // source-side swizzle
            int xrow = rowBase + xr;
            if (xrow >= M) xrow = M - 1;               // clamp (no OOB DMA)
            gload16(X + xrow * 128 + kk * 32 + kc * 4,
                    XsB + (t * 256 + wv * 64) * 4);    // uniform base; +lane*16 auto
        }
        #pragma unroll
        for (int t = 0; t < NWC; ++t) {
            const int d = t * 256 + tid;
            gload16(Wm + kk * 32 * BN + d * 4,
                    WsB + (t * 256 + wv * 64) * 4);
        }
    };

    float4 aA[4], aB[4];
    #pragma unroll
    for (int j = 0; j < 4; ++j) { aA[j] = {0,0,0,0}; aB[j] = {0,0,0,0}; }

    stage(0, 0);
    __syncthreads();                                   // compiler drains vmcnt(0)
    for (int kk = 0; kk < 4; ++kk) {
        const int cur = kk & 1;
        if (kk < 3) stage(kk + 1, cur ^ 1);
        const float* XsC = &Xs[cur][0];
        const float* WsC = &Ws[cur][0];
        auto step = [&](int k, float xv0, float xv1) {
            const float* wp = WsC + k * BN + g4;
            const float4 w0 = *reinterpret_cast<const float4*>(wp);
            const float4 w1 = *reinterpret_cast<const float4*>(wp + CS);
            const float4 w2 = *reinterpret_cast<const float4*>(wp + 2 * CS);
            const float4 w3 = *reinterpret_cast<const float4*>(wp + 3 * CS);
            aA[0].x += xv0*w0.x; aA[0].y += xv0*w0.y; aA[0].z += xv0*w0.z; aA[0].w += xv0*w0.w;
            aA[1].x += xv0*w1.x; aA[1].y += xv0*w1.y; aA[1].z += xv0*w1.z; aA[1].w += xv0*w1.w;
            aA[2].x += xv0*w2.x; aA[2].y += xv0*w2.y; aA[2].z += xv0*w2.z; aA[2].w += xv0*w2.w;
            aA[3].x += xv0*w3.x; aA[3].y += xv0*w3.y; aA[3].z += xv0*w3.z; aA[3].w += xv0*w3.w;
            aB[0].x += xv1*w0.x; aB[0].y += xv1*w0.y; aB[0].z += xv1*w0.z; aB[0].w += xv1*w0.w;
            aB[1].x += xv1*w1.x; aB[1].y += xv1*w1.y; aB[1].z += xv1*w1.z; aB[1].w += xv1*w1.w;
            aB[2].x += xv1*w2.x; aB[2].y += xv1*w2.y; aB[2].z += xv1*w2.z; aB[2].w += xv1*w2.w;
            aB[3].x += xv1*w3.x; aB[3].y += xv1*w3.y; aB[3].z += xv1*w3.z; aB[3].w += xv1*w3.w;
        };
        #pragma unroll
        for (int kc = 0; kc < 8; ++kc) {
            const float4 xq0 = *reinterpret_cast<const float4*>(
                XsC + (r * 8 + (kc ^ rr)) * 4);
            const float4 xq1 = *reinterpret_cast<const float4*>(
                XsC + ((r + NR) * 8 + (kc ^ rr)) * 4);
            step(kc * 4 + 0, xq0.x, xq1.x);
            step(kc * 4 + 1, xq0.y, xq1.y);
            step(kc * 4 + 2, xq0.z, xq1.z);
            step(kc * 4 + 3, xq0.w, xq1.w);
        }
        __syncthreads();
    }

    const float4* avs = reinterpret_cast<const float4*>(attS);
    const float4* avd = reinterpret_cast<const float4*>(attD);
    #pragma unroll
    for (int p = 0; p < 2; ++p) {
        const float4* a = p ? aB : aA;
        const int grow = rowBase + r + NR * p;
        if (grow < M) {
            if (WRITE_Y) {
                float* yrow = &Y[grow * BN + g4];
                *reinterpret_cast<float4*>(yrow)          = a[0];
                *reinterpret_cast<float4*>(yrow + CS)     = a[1];
                *reinterpret_cast<float4*>(yrow + 2 * CS) = a[2];
                *reinterpret_cast<float4*>(yrow + 3 * CS) = a[3];
            }
            if (WRITE_H16) {
                uint32* hrow = &H16[grow * (BN / 2)];
                #pragma unroll
                for (int j = 0; j < 4; ++j) {
                    uint2 u;
                    u.x = packbf2(a[j].x, a[j].y);
                    u.y = packbf2(a[j].z, a[j].w);
                    *reinterpret_cast<uint2*>(&hrow[g * 2 + j * (CS / 2)]) = u;
                }
            }
        }
        float ps0 = dot4(a[0], avs[g])              + dot4(a[1], avs[g + GROUPS]);
        float ps1 = dot4(a[2], avs[g + 2 * GROUPS]) + dot4(a[3], avs[g + 3 * GROUPS]);
        float pd0 = dot4(a[0], avd[g])              + dot4(a[1], avd[g + GROUPS]);
        float pd1 = dot4(a[2], avd[g + 2 * GROUPS]) + dot4(a[3], avd[g + 3 * GROUPS]);
        #pragma unroll
        for (int d = 1; d < GROUPS; d <<= 1) {
            ps0 += __shfl_xor(ps0, d);
            ps1 += __shfl_xor(ps1, d);
            pd0 += __shfl_xor(pd0, d);
            pd1 += __shfl_xor(pd1, d);
        }
        if (g == 0 && grow < M) {
            asrcO[grow * 2]     = ps0;
            asrcO[grow * 2 + 1] = ps1;
            adstO[grow * 2]     = pd0;
            adstO[grow * 2 + 1] = pd1;
        }
    }
}

// ---------------- fused per-dst exact softmax + aggregation (layer 1) ---------
// one wave per dst; lane owns chans {2*lane, 2*lane+1}; head h = lane>>5.
// phase1: wave-parallel max (scores cached in regs); phase2: no-rescale accum.
// All H reads from bf16 H16. Epilogue applies relu(. + bias1) so gemm2 can
// DMA-stage out1 without a load-transform.
__global__ __launch_bounds__(256) void gat_dst1(const int* __restrict__ esrc,
                                                const int* __restrict__ offs,
                                                const uint32* __restrict__ H16,
                                                const float* __restrict__ asrc,
                                                const float* __restrict__ adst,
                                                const float* __restrict__ bias1,
                                                float* __restrict__ out) {
    const int wid  = (blockIdx.x * blockDim.x + threadIdx.x) >> 6;
    const int lane = threadIdx.x & 63;
    if (wid >= NN) return;
    const int dst = wid;
    const int beg = offs[dst];
    const int end = (dst == NN - 1) ? NE : offs[dst + 1];
    const int deg = end - beg;
    const float2 ad = *reinterpret_cast<const float2*>(&adst[dst * 2]);

    int   s0  = 0;
    float pe0 = -INFINITY, pe1 = -INFINITY;
    float m0  = -INFINITY, m1  = -INFINITY;
    for (int j = lane; j < deg; j += 64) {
        const int s = esrc[beg + j];
        const float2 a = *reinterpret_cast<const float2*>(&asrc[s * 2]);
        const float f0 = lrelu(a.x + ad.x);
        const float f1 = lrelu(a.y + ad.y);
        if (j == lane) { s0 = s; pe0 = f0; pe1 = f1; }
        m0 = fmaxf(m0, f0); m1 = fmaxf(m1, f1);
    }
    const float2 aself = *reinterpret_cast<const float2*>(&asrc[dst * 2]);
    const float es0 = lrelu(aself.x + ad.x);
    const float es1 = lrelu(aself.y + ad.y);
    m0 = fmaxf(m0, es0); m1 = fmaxf(m1, es1);
    #pragma unroll
    for (int d = 1; d < 64; d <<= 1) {
        m0 = fmaxf(m0, __shfl_xor(m0, d));
        m1 = fmaxf(m1, __shfl_xor(m1, d));
    }
    const int h = lane >> 5;
    const float m = h ? m1 : m0;

    float l;
    float2 acc;
    {
        const float px = __expf((h ? es1 : es0) - m);
        l = px;
        const uint32 u = H16[dst * 64 + lane];
        acc.x = px * __uint_as_float(u << 16);
        acc.y = px * __uint_as_float(u & 0xffff0000u);
    }
    const int jmax = deg < 64 ? deg : 64;
    for (int j = 0; j < jmax; ++j) {
        const int s = __shfl(s0, j);
        const float t0 = __shfl(pe0, j), t1 = __shfl(pe1, j);
        const float p = __expf((h ? t1 : t0) - m);
        const uint32 u = H16[s * 64 + lane];
        l += p;
        acc.x += p * __uint_as_float(u << 16);
        acc.y += p * __uint_as_float(u & 0xffff0000u);
    }
    for (int j = 64; j < deg; ++j) {          // astronomically rare (deg>64)
        const int s = esrc[beg + j];
        const float2 a = *reinterpret_cast<const float2*>(&asrc[s * 2]);
        const float p = __expf(lrelu((h ? a.y : a.x) + (h ? ad.y : ad.x)) - m);
        const uint32 u = H16[s * 64 + lane];
        l += p;
        acc.x += p * __uint_as_float(u << 16);
        acc.y += p * __uint_as_float(u & 0xffff0000u);
    }
    const float inv = 1.0f / (l + 1e-16f);
    const float2 bb = *reinterpret_cast<const float2*>(&bias1[lane * 2]);
    float2 res;
    res.x = fmaxf(acc.x * inv + bb.x, 0.0f);   // fused relu(out1 + b1)
    res.y = fmaxf(acc.y * inv + bb.y, 0.0f);
    *reinterpret_cast<float2*>(&out[dst * 128 + lane * 2]) = res;
}

// ---------------- layer 2: same structure + head-mean; f32 H [N,64] -----------
__global__ __launch_bounds__(256) void gat_dst2(const int* __restrict__ esrc,
                                                const int* __restrict__ offs,
                                                const float* __restrict__ Hf,
                                                const float* __restrict__ asrc,
                                                const float* __restrict__ adst,
                                                const float* __restrict__ bias,
                                                float* __restrict__ out) {
    const int wid  = (blockIdx.x * blockDim.x + threadIdx.x) >> 6;
    const int lane = threadIdx.x & 63;
    if (wid >= NN) return;
    const int dst = wid;
    const int beg = offs[dst];
    const int end = (dst == NN - 1) ? NE : offs[dst + 1];
    const int deg = end - beg;
    const float2 ad = *reinterpret_cast<const float2*>(&adst[dst * 2]);

    int   s0  = 0;
    float pe0 = -INFINITY, pe1 = -INFINITY;
    float m0  = -INFINITY, m1  = -INFINITY;
    for (int j = lane; j < deg; j += 64) {
        const int s = esrc[beg + j];
        const float2 a = *reinterpret_cast<const float2*>(&asrc[s * 2]);
        const float f0 = lrelu(a.x + ad.x);
        const float f1 = lrelu(a.y + ad.y);
        if (j == lane) { s0 = s; pe0 = f0; pe1 = f1; }
        m0 = fmaxf(m0, f0); m1 = fmaxf(m1, f1);
    }
    const float2 aself = *reinterpret_cast<const float2*>(&asrc[dst * 2]);
    const float es0 = lrelu(aself.x + ad.x);
    const float es1 = lrelu(aself.y + ad.y);
    m0 = fmaxf(m0, es0); m1 = fmaxf(m1, es1);
    #pragma unroll
    for (int d = 1; d < 64; d <<= 1) {
        m0 = fmaxf(m0, __shfl_xor(m0, d));
        m1 = fmaxf(m1, __shfl_xor(m1, d));
    }
    const int h = lane >> 5;
    const float m = h ? m1 : m0;

    float l, acc;
    {
        const float px = __expf((h ? es1 : es0) - m);
        l = px;
        acc = px * Hf[dst * 64 + lane];
    }
    const int jmax = deg < 64 ? deg : 64;
    for (int j = 0; j < jmax; ++j) {
        const int s = __shfl(s0, j);
        const float t0 = __shfl(pe0, j), t1 = __shfl(pe1, j);
        const float p = __expf((h ? t1 : t0) - m);
        const float hv = Hf[s * 64 + lane];
        l += p;
        acc += p * hv;
    }
    for (int j = 64; j < deg; ++j) {          // astronomically rare
        const int s = esrc[beg + j];
        const float2 a = *reinterpret_cast<const float2*>(&asrc[s * 2]);
        const float p = __expf(lrelu((h ? a.y : a.x) + (h ? ad.y : ad.x)) - m);
        l += p;
        acc += p * Hf[s * 64 + lane];
    }
    float r = acc / (l + 1e-16f);
    r += __shfl_xor(r, 32);                   // combine heads
    if (lane < 32) out[dst * 32 + lane] = 0.5f * r + bias[lane];
}

// ---------------- launch ----------------
extern "C" void kernel_launch(void* const* d_in, const int* in_sizes, int n_in,
                              void* d_out, int out_size, void* d_ws, size_t ws_size,
                              hipStream_t stream) {
    const float* x   = (const float*)d_in[0];
    const int*   ei  = (const int*)d_in[1];
    const float* W1  = (const float*)d_in[2];
    const float* as1 = (const float*)d_in[3];
    const float* ad1 = (const float*)d_in[4];
    const float* b1  = (const float*)d_in[5];
    const float* W2  = (const float*)d_in[6];
    const float* as2 = (const float*)d_in[7];
    const float* ad2 = (const float*)d_in[8];
    const float* b2  = (const float*)d_in[9];
    float* out = (float*)d_out;

    // Workspace: 14.15 M floats = 56.6 MB (round-8/9 proven layout).
    float* ws = (float*)d_ws;
    size_t off = 0;
    float* out1  = ws + off; off += (size_t)NN * FIN;   // [N,128] relu(out1+b1)
    float* h2f   = ws + off; off += (size_t)NN * C1;    // [N,64]  layer2 H (f32)
    float* asrc1 = ws + off; off += (size_t)NN * NH;
    float* adst1 = ws + off; off += (size_t)NN * NH;
    float* asrc2 = ws + off; off += (size_t)NN * NH;
    float* adst2 = ws + off; off += (size_t)NN * NH;
    uint32* h16  = (uint32*)(ws + off); off += (size_t)NN * 64;  // bf16 [N,128]
    int* ibase = (int*)(ws + off);
    int* deg   = ibase;                 // [NN]  \ adjacent: one zero_ints
    int* fill  = ibase + NN;            // [NN]  /
    int* offs  = ibase + 2 * NN;        // [NN]
    int* bsum  = ibase + 3 * NN;        // [256]
    int* esrc  = ibase + 3 * NN + 256;  // [NE]

    const int B = 256;
    constexpr int NB_SCAN = (NN + 255) / 256;   // 196

    // ---- CSR build (shared by both layers) ----
    zero_ints<<<128, B, 0, stream>>>(deg, 2 * NN);   // deg + fill
    hist_dst<<<(NE + B - 1) / B, B, 0, stream>>>(ei, deg);
    scan_blocks<<<NB_SCAN, 256, 0, stream>>>(deg, offs, bsum);
    scan_bsums<<<1, 256, 0, stream>>>(bsum, NB_SCAN);
    scan_add<<<NB_SCAN, 256, 0, stream>>>(offs, bsum);
    csr_scatter<<<(NE + B - 1) / B, B, 0, stream>>>(ei, offs, fill, esrc);

    // ---- layer 1 ----  (gemm writes bf16 H only; BM=64 -> 782 blocks)
    gemm_k128<128, false, true><<<(NN + 63) / 64, B, 0, stream>>>(
        x, W1, as1, ad1, nullptr, h16, asrc1, adst1, NN);
    gat_dst1<<<(NN * 64 + B - 1) / B, B, 0, stream>>>(
        esrc, offs, h16, asrc1, adst1, b1, out1);

    // ---- layer 2 ----  (gemm writes f32 Y only; BM=128 -> 391 blocks)
    gemm_k128<64, true, false><<<(NN + 127) / 128, B, 0, stream>>>(
        out1, W2, as2, ad2, h2f, nullptr, asrc2, adst2, NN);
    gat_dst2<<<(NN * 64 + B - 1) / B, B, 0, stream>>>(
        esrc, offs, h2f, asrc2, adst2, b2, out);
}

// Round 12
// 322.355 us; speedup vs baseline: 2.0112x; 1.1369x over previous
//
#include <hip/hip_runtime.h>
#include <hip/hip_bf16.h>

// Problem constants (fixed by the reference)
#define NN 50000
#define FIN 128
#define NH 2
#define C1 64
#define C2 32
#define NE 800000
#define NEG 0.2f

typedef unsigned int uint32;

__device__ __forceinline__ float lrelu(float v) { return v > 0.0f ? v : NEG * v; }
__device__ __forceinline__ float dot4(float4 a, float4 b) {
    return a.x * b.x + a.y * b.y + a.z * b.z + a.w * b.w;
}
// pack two f32 -> bf16x2 (round-to-nearest-even; inputs finite)
__device__ __forceinline__ uint32 packbf2(float a, float b) {
    uint32 ua = __float_as_uint(a), ub = __float_as_uint(b);
    ua += 0x7fffu + ((ua >> 16) & 1u);
    ub += 0x7fffu + ((ub >> 16) & 1u);
    return (ua >> 16) | (ub & 0xffff0000u);
}
// async 16B global -> LDS DMA. LDS dest: wave-uniform base + lane*16 (m104).
__device__ __forceinline__ void gload16(const float* g, float* l) {
    __builtin_amdgcn_global_load_lds(
        (const __attribute__((address_space(1))) unsigned int*)g,
        (__attribute__((address_space(3))) unsigned int*)l, 16, 0, 0);
}

// ---------------- CSR build ----------------
__global__ void zero_ints(int* __restrict__ a, int n) {
    for (int i = blockIdx.x * blockDim.x + threadIdx.x; i < n;
         i += gridDim.x * blockDim.x) a[i] = 0;
}

__global__ void hist_dst(const int* __restrict__ ei, int* __restrict__ deg) {
    const int i = blockIdx.x * blockDim.x + threadIdx.x;
    if (i >= NE) return;
    atomicAdd(&deg[ei[NE + i]], 1);
}

__global__ void scan_blocks(const int* __restrict__ deg, int* __restrict__ offs,
                            int* __restrict__ bsum) {
    __shared__ int sm[256];
    const int t = threadIdx.x;
    const int i = blockIdx.x * 256 + t;
    const int v = (i < NN) ? deg[i] : 0;
    sm[t] = v;
    __syncthreads();
    int x = v;
    #pragma unroll
    for (int d = 1; d < 256; d <<= 1) {
        const int y = (t >= d) ? sm[t - d] : 0;
        __syncthreads();
        x += y; sm[t] = x;
        __syncthreads();
    }
    if (i < NN) offs[i] = x - v;
    if (t == 255) bsum[blockIdx.x] = x;
}

__global__ void scan_bsums(int* __restrict__ bsum, int nb) {
    __shared__ int sm[256];
    const int t = threadIdx.x;
    const int v = (t < nb) ? bsum[t] : 0;
    sm[t] = v;
    __syncthreads();
    int x = v;
    #pragma unroll
    for (int d = 1; d < 256; d <<= 1) {
        const int y = (t >= d) ? sm[t - d] : 0;
        __syncthreads();
        x += y; sm[t] = x;
        __syncthreads();
    }
    if (t < nb) bsum[t] = x - v;
}

__global__ void scan_add(int* __restrict__ offs, const int* __restrict__ bsum) {
    const int i = blockIdx.x * 256 + threadIdx.x;
    if (i < NN) offs[i] += bsum[blockIdx.x];
}

__global__ void csr_scatter(const int* __restrict__ ei, const int* __restrict__ offs,
                            int* __restrict__ fill, int* __restrict__ esrc) {
    const int i = blockIdx.x * blockDim.x + threadIdx.x;
    if (i >= NE) return;
    const int src = ei[i], dst = ei[NE + i];
    const int pos = offs[dst] + atomicAdd(&fill[dst], 1);
    esrc[pos] = src;
}

// ------- GEMM (K=128): global_load_lds dbuf staging, RPT=2 reg blocking -------
// X stride fixed 128 (both layers). Lane g owns 4 float4 col chunks at stride
// CS=BN/4 (conflict-free ds_read_b128 on W). X stored source-swizzled:
// LDS slot d holds X[row=d>>3][f4col = (d&7) ^ (row&7)]; read with same XOR.
template<int BN, bool WRITE_Y, bool WRITE_H16>
__global__ __launch_bounds__(256, 2) void gemm_k128(const float* __restrict__ X,
                                                    const float* __restrict__ Wm,
                                                    const float* __restrict__ attS,
                                                    const float* __restrict__ attD,
                                                    float* __restrict__ Y,
                                                    uint32* __restrict__ H16,
                                                    float* __restrict__ asrcO,
                                                    float* __restrict__ adstO, int M) {
    constexpr int GROUPS = BN / 16;      // 8 (BN=128) or 4 (BN=64)
    constexpr int NR = 256 / GROUPS;     // 32 or 64
    constexpr int BM = NR * 2;           // 64 or 128 rows/block (RPT=2)
    constexpr int CS = BN / 4;
    constexpr int NXC = BM / 32;         // X 16B-DMAs per thread per kk (2 or 4)
    constexpr int NWC = BN / 32;         // W 16B-DMAs per thread per kk (4 or 2)
    __shared__ __align__(16) float Xs[2][BM * 32];
    __shared__ __align__(16) float Ws[2][32 * BN];

    const int tid = threadIdx.x;
    const int r  = tid / GROUPS;         // 0..NR-1 (owns rows r, r+NR)
    const int g  = tid % GROUPS;
    const int g4 = g * 4;
    const int wv = tid >> 6;             // wave id (uniform per wave)
    const int rowBase = blockIdx.x * BM;
    const int rr = r & 7;                // (r+NR)&7 == r&7 since NR%8==0

    auto stage = [&](int kk, int b) {
        float* XsB = &Xs[b][0];
        float* WsB = &Ws[b][0];
        #pragma unroll
        for (int t = 0; t < NXC; ++t) {
            const int d  = t * 256 + tid;              // slot id
            const int xr = d >> 3;
            const int kc = (d & 7) ^ (xr & 7);         // source-side swizzle
            int xrow = rowBase + xr;
            if (xrow >= M) xrow = M - 1;               // clamp (no OOB DMA)
            gload16(X + xrow * 128 + kk * 32 + kc * 4,
                    XsB + (t * 256 + wv * 64) * 4);    // uniform base; +lane*16 auto
        }
        #pragma unroll
        for (int t = 0; t < NWC; ++t) {
            const int d = t * 256 + tid;
            gload16(Wm + kk * 32 * BN + d * 4,
                    WsB + (t * 256 + wv * 64) * 4);
        }
    };

    float4 aA[4], aB[4];
    #pragma unroll
    for (int j = 0; j < 4; ++j) { aA[j] = {0,0,0,0}; aB[j] = {0,0,0,0}; }

    stage(0, 0);
    __syncthreads();                                   // compiler drains vmcnt(0)
    for (int kk = 0; kk < 4; ++kk) {
        const int cur = kk & 1;
        if (kk < 3) stage(kk + 1, cur ^ 1);
        const float* XsC = &Xs[cur][0];
        const float* WsC = &Ws[cur][0];
        auto step = [&](int k, float xv0, float xv1) {
            const float* wp = WsC + k * BN + g4;
            const float4 w0 = *reinterpret_cast<const float4*>(wp);
            const float4 w1 = *reinterpret_cast<const float4*>(wp + CS);
            const float4 w2 = *reinterpret_cast<const float4*>(wp + 2 * CS);
            const float4 w3 = *reinterpret_cast<const float4*>(wp + 3 * CS);
            aA[0].x += xv0*w0.x; aA[0].y += xv0*w0.y; aA[0].z += xv0*w0.z; aA[0].w += xv0*w0.w;
            aA[1].x += xv0*w1.x; aA[1].y += xv0*w1.y; aA[1].z += xv0*w1.z; aA[1].w += xv0*w1.w;
            aA[2].x += xv0*w2.x; aA[2].y += xv0*w2.y; aA[2].z += xv0*w2.z; aA[2].w += xv0*w2.w;
            aA[3].x += xv0*w3.x; aA[3].y += xv0*w3.y; aA[3].z += xv0*w3.z; aA[3].w += xv0*w3.w;
            aB[0].x += xv1*w0.x; aB[0].y += xv1*w0.y; aB[0].z += xv1*w0.z; aB[0].w += xv1*w0.w;
            aB[1].x += xv1*w1.x; aB[1].y += xv1*w1.y; aB[1].z += xv1*w1.z; aB[1].w += xv1*w1.w;
            aB[2].x += xv1*w2.x; aB[2].y += xv1*w2.y; aB[2].z += xv1*w2.z; aB[2].w += xv1*w2.w;
            aB[3].x += xv1*w3.x; aB[3].y += xv1*w3.y; aB[3].z += xv1*w3.z; aB[3].w += xv1*w3.w;
        };
        #pragma unroll
        for (int kc = 0; kc < 8; ++kc) {
            const float4 xq0 = *reinterpret_cast<const float4*>(
                XsC + (r * 8 + (kc ^ rr)) * 4);
            const float4 xq1 = *reinterpret_cast<const float4*>(
                XsC + ((r + NR) * 8 + (kc ^ rr)) * 4);
            step(kc * 4 + 0, xq0.x, xq1.x);
            step(kc * 4 + 1, xq0.y, xq1.y);
            step(kc * 4 + 2, xq0.z, xq1.z);
            step(kc * 4 + 3, xq0.w, xq1.w);
        }
        __syncthreads();
    }

    const float4* avs = reinterpret_cast<const float4*>(attS);
    const float4* avd = reinterpret_cast<const float4*>(attD);
    #pragma unroll
    for (int p = 0; p < 2; ++p) {
        const float4* a = p ? aB : aA;
        const int grow = rowBase + r + NR * p;
        if (grow < M) {
            if (WRITE_Y) {
                float* yrow = &Y[grow * BN + g4];
                *reinterpret_cast<float4*>(yrow)          = a[0];
                *reinterpret_cast<float4*>(yrow + CS)     = a[1];
                *reinterpret_cast<float4*>(yrow + 2 * CS) = a[2];
                *reinterpret_cast<float4*>(yrow + 3 * CS) = a[3];
            }
            if (WRITE_H16) {
                uint32* hrow = &H16[grow * (BN / 2)];
                #pragma unroll
                for (int j = 0; j < 4; ++j) {
                    uint2 u;
                    u.x = packbf2(a[j].x, a[j].y);
                    u.y = packbf2(a[j].z, a[j].w);
                    *reinterpret_cast<uint2*>(&hrow[g * 2 + j * (CS / 2)]) = u;
                }
            }
        }
        float ps0 = dot4(a[0], avs[g])              + dot4(a[1], avs[g + GROUPS]);
        float ps1 = dot4(a[2], avs[g + 2 * GROUPS]) + dot4(a[3], avs[g + 3 * GROUPS]);
        float pd0 = dot4(a[0], avd[g])              + dot4(a[1], avd[g + GROUPS]);
        float pd1 = dot4(a[2], avd[g + 2 * GROUPS]) + dot4(a[3], avd[g + 3 * GROUPS]);
        #pragma unroll
        for (int d = 1; d < GROUPS; d <<= 1) {
            ps0 += __shfl_xor(ps0, d);
            ps1 += __shfl_xor(ps1, d);
            pd0 += __shfl_xor(pd0, d);
            pd1 += __shfl_xor(pd1, d);
        }
        if (g == 0 && grow < M) {
            asrcO[grow * 2]     = ps0;
            asrcO[grow * 2 + 1] = ps1;
            adstO[grow * 2]     = pd0;
            adstO[grow * 2 + 1] = pd1;
        }
    }
}

// ---------------- fused per-dst exact softmax + aggregation (layer 1) ---------
// one wave per dst; lane owns chans {2*lane, 2*lane+1}; head h = lane>>5.
// phase1: wave-parallel max; phase2: UNROLL-4 batched gathers (4 loads in
// flight/wave). NOTE: shuffle BOTH pe0,pe1 then select by h AFTER the shuffle --
// __shfl(h?pe1:pe0, j) evaluates the selector on the SOURCE lane (round-11 bug).
__global__ __launch_bounds__(256) void gat_dst1(const int* __restrict__ esrc,
                                                const int* __restrict__ offs,
                                                const uint32* __restrict__ H16,
                                                const float* __restrict__ asrc,
                                                const float* __restrict__ adst,
                                                const float* __restrict__ bias1,
                                                float* __restrict__ out) {
    const int wid  = (blockIdx.x * blockDim.x + threadIdx.x) >> 6;
    const int lane = threadIdx.x & 63;
    if (wid >= NN) return;
    const int dst = wid;
    const int beg = offs[dst];
    const int end = (dst == NN - 1) ? NE : offs[dst + 1];
    const int deg = end - beg;
    const float2 ad = *reinterpret_cast<const float2*>(&adst[dst * 2]);

    int   s0  = 0;
    float pe0 = -INFINITY, pe1 = -INFINITY;
    float m0  = -INFINITY, m1  = -INFINITY;
    for (int j = lane; j < deg; j += 64) {
        const int s = esrc[beg + j];
        const float2 a = *reinterpret_cast<const float2*>(&asrc[s * 2]);
        const float f0 = lrelu(a.x + ad.x);
        const float f1 = lrelu(a.y + ad.y);
        if (j == lane) { s0 = s; pe0 = f0; pe1 = f1; }
        m0 = fmaxf(m0, f0); m1 = fmaxf(m1, f1);
    }
    const float2 aself = *reinterpret_cast<const float2*>(&asrc[dst * 2]);
    const float es0 = lrelu(aself.x + ad.x);
    const float es1 = lrelu(aself.y + ad.y);
    m0 = fmaxf(m0, es0); m1 = fmaxf(m1, es1);
    #pragma unroll
    for (int d = 1; d < 64; d <<= 1) {
        m0 = fmaxf(m0, __shfl_xor(m0, d));
        m1 = fmaxf(m1, __shfl_xor(m1, d));
    }
    const int h = lane >> 5;
    const float m = h ? m1 : m0;

    float l;
    float2 acc;
    {
        const float px = __expf((h ? es1 : es0) - m);
        l = px;
        const uint32 u = H16[dst * 64 + lane];
        acc.x = px * __uint_as_float(u << 16);
        acc.y = px * __uint_as_float(u & 0xffff0000u);
    }
    const int jmax = deg < 64 ? deg : 64;
    int j = 0;
    for (; j + 3 < jmax; j += 4) {
        const int sa = __shfl(s0, j),     sb = __shfl(s0, j + 1);
        const int sc = __shfl(s0, j + 2), sd = __shfl(s0, j + 3);
        const float ta0 = __shfl(pe0, j),     ta1 = __shfl(pe1, j);
        const float tb0 = __shfl(pe0, j + 1), tb1 = __shfl(pe1, j + 1);
        const float tc0 = __shfl(pe0, j + 2), tc1 = __shfl(pe1, j + 2);
        const float td0 = __shfl(pe0, j + 3), td1 = __shfl(pe1, j + 3);
        const uint32 ua = H16[sa * 64 + lane];        // 4 gathers in flight
        const uint32 ub = H16[sb * 64 + lane];
        const uint32 uc = H16[sc * 64 + lane];
        const uint32 ud = H16[sd * 64 + lane];
        const float pa = __expf((h ? ta1 : ta0) - m);
        const float pb = __expf((h ? tb1 : tb0) - m);
        const float pc = __expf((h ? tc1 : tc0) - m);
        const float pd = __expf((h ? td1 : td0) - m);
        l += (pa + pb) + (pc + pd);
        acc.x += pa * __uint_as_float(ua << 16) + pb * __uint_as_float(ub << 16)
               + pc * __uint_as_float(uc << 16) + pd * __uint_as_float(ud << 16);
        acc.y += pa * __uint_as_float(ua & 0xffff0000u) + pb * __uint_as_float(ub & 0xffff0000u)
               + pc * __uint_as_float(uc & 0xffff0000u) + pd * __uint_as_float(ud & 0xffff0000u);
    }
    for (; j < jmax; ++j) {
        const int s = __shfl(s0, j);
        const float t0 = __shfl(pe0, j), t1 = __shfl(pe1, j);
        const float p = __expf((h ? t1 : t0) - m);
        const uint32 u = H16[s * 64 + lane];
        l += p;
        acc.x += p * __uint_as_float(u << 16);
        acc.y += p * __uint_as_float(u & 0xffff0000u);
    }
    for (int j2 = 64; j2 < deg; ++j2) {       // astronomically rare (deg>64)
        const int s = esrc[beg + j2];
        const float2 a = *reinterpret_cast<const float2*>(&asrc[s * 2]);
        const float p = __expf(lrelu((h ? a.y : a.x) + (h ? ad.y : ad.x)) - m);
        const uint32 u = H16[s * 64 + lane];
        l += p;
        acc.x += p * __uint_as_float(u << 16);
        acc.y += p * __uint_as_float(u & 0xffff0000u);
    }
    const float inv = 1.0f / (l + 1e-16f);
    const float2 bb = *reinterpret_cast<const float2*>(&bias1[lane * 2]);
    float2 res;
    res.x = fmaxf(acc.x * inv + bb.x, 0.0f);   // fused relu(out1 + b1)
    res.y = fmaxf(acc.y * inv + bb.y, 0.0f);
    *reinterpret_cast<float2*>(&out[dst * 128 + lane * 2]) = res;
}

// ---------------- layer 2: same structure + head-mean; f32 H [N,64] -----------
__global__ __launch_bounds__(256) void gat_dst2(const int* __restrict__ esrc,
                                                const int* __restrict__ offs,
                                                const float* __restrict__ Hf,
                                                const float* __restrict__ asrc,
                                                const float* __restrict__ adst,
                                                const float* __restrict__ bias,
                                                float* __restrict__ out) {
    const int wid  = (blockIdx.x * blockDim.x + threadIdx.x) >> 6;
    const int lane = threadIdx.x & 63;
    if (wid >= NN) return;
    const int dst = wid;
    const int beg = offs[dst];
    const int end = (dst == NN - 1) ? NE : offs[dst + 1];
    const int deg = end - beg;
    const float2 ad = *reinterpret_cast<const float2*>(&adst[dst * 2]);

    int   s0  = 0;
    float pe0 = -INFINITY, pe1 = -INFINITY;
    float m0  = -INFINITY, m1  = -INFINITY;
    for (int j = lane; j < deg; j += 64) {
        const int s = esrc[beg + j];
        const float2 a = *reinterpret_cast<const float2*>(&asrc[s * 2]);
        const float f0 = lrelu(a.x + ad.x);
        const float f1 = lrelu(a.y + ad.y);
        if (j == lane) { s0 = s; pe0 = f0; pe1 = f1; }
        m0 = fmaxf(m0, f0); m1 = fmaxf(m1, f1);
    }
    const float2 aself = *reinterpret_cast<const float2*>(&asrc[dst * 2]);
    const float es0 = lrelu(aself.x + ad.x);
    const float es1 = lrelu(aself.y + ad.y);
    m0 = fmaxf(m0, es0); m1 = fmaxf(m1, es1);
    #pragma unroll
    for (int d = 1; d < 64; d <<= 1) {
        m0 = fmaxf(m0, __shfl_xor(m0, d));
        m1 = fmaxf(m1, __shfl_xor(m1, d));
    }
    const int h = lane >> 5;
    const float m = h ? m1 : m0;

    float l, acc;
    {
        const float px = __expf((h ? es1 : es0) - m);
        l = px;
        acc = px * Hf[dst * 64 + lane];
    }
    const int jmax = deg < 64 ? deg : 64;
    int j = 0;
    for (; j + 3 < jmax; j += 4) {
        const int sa = __shfl(s0, j),     sb = __shfl(s0, j + 1);
        const int sc = __shfl(s0, j + 2), sd = __shfl(s0, j + 3);
        const float ta0 = __shfl(pe0, j),     ta1 = __shfl(pe1, j);
        const float tb0 = __shfl(pe0, j + 1), tb1 = __shfl(pe1, j + 1);
        const float tc0 = __shfl(pe0, j + 2), tc1 = __shfl(pe1, j + 2);
        const float td0 = __shfl(pe0, j + 3), td1 = __shfl(pe1, j + 3);
        const float ha = Hf[sa * 64 + lane];          // 4 gathers in flight
        const float hb = Hf[sb * 64 + lane];
        const float hc = Hf[sc * 64 + lane];
        const float hd = Hf[sd * 64 + lane];
        const float pa = __expf((h ? ta1 : ta0) - m);
        const float pb = __expf((h ? tb1 : tb0) - m);
        const float pc = __expf((h ? tc1 : tc0) - m);
        const float pd = __expf((h ? td1 : td0) - m);
        l += (pa + pb) + (pc + pd);
        acc += pa * ha + pb * hb + pc * hc + pd * hd;
    }
    for (; j < jmax; ++j) {
        const int s = __shfl(s0, j);
        const float t0 = __shfl(pe0, j), t1 = __shfl(pe1, j);
        const float p = __expf((h ? t1 : t0) - m);
        const float hv = Hf[s * 64 + lane];
        l += p;
        acc += p * hv;
    }
    for (int j2 = 64; j2 < deg; ++j2) {       // astronomically rare
        const int s = esrc[beg + j2];
        const float2 a = *reinterpret_cast<const float2*>(&asrc[s * 2]);
        const float p = __expf(lrelu((h ? a.y : a.x) + (h ? ad.y : ad.x)) - m);
        l += p;
        acc += p * Hf[s * 64 + lane];
    }
    float r = acc / (l + 1e-16f);
    r += __shfl_xor(r, 32);                   // combine heads
    if (lane < 32) out[dst * 32 + lane] = 0.5f * r + bias[lane];
}

// ---------------- launch ----------------
extern "C" void kernel_launch(void* const* d_in, const int* in_sizes, int n_in,
                              void* d_out, int out_size, void* d_ws, size_t ws_size,
                              hipStream_t stream) {
    const float* x   = (const float*)d_in[0];
    const int*   ei  = (const int*)d_in[1];
    const float* W1  = (const float*)d_in[2];
    const float* as1 = (const float*)d_in[3];
    const float* ad1 = (const float*)d_in[4];
    const float* b1  = (const float*)d_in[5];
    const float* W2  = (const float*)d_in[6];
    const float* as2 = (const float*)d_in[7];
    const float* ad2 = (const float*)d_in[8];
    const float* b2  = (const float*)d_in[9];
    float* out = (float*)d_out;

    // Workspace: 14.15 M floats = 56.6 MB (round-8/9/10 proven layout).
    float* ws = (float*)d_ws;
    size_t off = 0;
    float* out1  = ws + off; off += (size_t)NN * FIN;   // [N,128] relu(out1+b1)
    float* h2f   = ws + off; off += (size_t)NN * C1;    // [N,64]  layer2 H (f32)
    float* asrc1 = ws + off; off += (size_t)NN * NH;
    float* adst1 = ws + off; off += (size_t)NN * NH;
    float* asrc2 = ws + off; off += (size_t)NN * NH;
    float* adst2 = ws + off; off += (size_t)NN * NH;
    uint32* h16  = (uint32*)(ws + off); off += (size_t)NN * 64;  // bf16 [N,128]
    int* ibase = (int*)(ws + off);
    int* deg   = ibase;                 // [NN]  \ adjacent: one zero_ints
    int* fill  = ibase + NN;            // [NN]  /
    int* offs  = ibase + 2 * NN;        // [NN]
    int* bsum  = ibase + 3 * NN;        // [256]
    int* esrc  = ibase + 3 * NN + 256;  // [NE]

    const int B = 256;
    constexpr int NB_SCAN = (NN + 255) / 256;   // 196

    // ---- CSR build (shared by both layers) ----
    zero_ints<<<128, B, 0, stream>>>(deg, 2 * NN);   // deg + fill
    hist_dst<<<(NE + B - 1) / B, B, 0, stream>>>(ei, deg);
    scan_blocks<<<NB_SCAN, 256, 0, stream>>>(deg, offs, bsum);
    scan_bsums<<<1, 256, 0, stream>>>(bsum, NB_SCAN);
    scan_add<<<NB_SCAN, 256, 0, stream>>>(offs, bsum);
    csr_scatter<<<(NE + B - 1) / B, B, 0, stream>>>(ei, offs, fill, esrc);

    // ---- layer 1 ----  (gemm writes bf16 H only; BM=64 -> 782 blocks)
    gemm_k128<128, false, true><<<(NN + 63) / 64, B, 0, stream>>>(
        x, W1, as1, ad1, nullptr, h16, asrc1, adst1, NN);
    gat_dst1<<<(NN * 64 + B - 1) / B, B, 0, stream>>>(
        esrc, offs, h16, asrc1, adst1, b1, out1);

    // ---- layer 2 ----  (gemm writes f32 Y only; BM=128 -> 391 blocks)
    gemm_k128<64, true, false><<<(NN + 127) / 128, B, 0, stream>>>(
        out1, W2, as2, ad2, h2f, nullptr, asrc2, adst2, NN);
    gat_dst2<<<(NN * 64 + B - 1) / B, B, 0, stream>>>(
        esrc, offs, h2f, asrc2, adst2, b2, out);
}